// Round 6
// baseline (120.536 us; speedup 1.0000x reference)
//
#include <hip/hip_runtime.h>
#include <math.h>

#define NB 2
#define NN 192
#define DIMX 256
#define HID 1024
#define NROWS (NB * NN)            // 384
#define SCALING 0.17677669529663687f  // 1/sqrt(32)
#define EPS 1e-5f

// workspace layout (float offsets)
#define OFF_KK    0                              // k-part, NROWS*256
#define OFF_QV    (OFF_KK + NROWS * DIMX)        // float2 q,v  NROWS*256*2
#define OFF_TSORT (OFF_QV + NROWS * DIMX * 2)    // 1024
#define OFF_IDX   (OFF_TSORT + HID)              // 1024 ints
#define OFF_SC    (OFF_IDX + HID)                // float2 (HID+1)*256*2
#define OFF_ATT   (OFF_SC + (HID + 1) * DIMX * 2)
#define OFF_WB    (OFF_ATT + NROWS * DIMX)       // 920064: bf16 weights (uints)
// bf16 regions in uints (2 weights per uint):
#define WB_QKV 0        // 98304 uints (256x768)
#define WB_WO  98304    // 32768  (256x256)
#define WB_WF1 131072   // 131072 (256x1024)
#define WB_WF2 262144   // 131072 (1024x256)
#define WB_TOT 393216
// end = OFF_WB + 393216 = 1,313,280 floats ≈ 5.25 MB

__device__ inline unsigned int f2b(float f) {
  const unsigned int u = __float_as_uint(f);
  return (u + 0x7fffu + ((u >> 16) & 1u)) >> 16;
}

// ---------------- K0: convert weights to packed bf16 ----------------
__global__ __launch_bounds__(1024) void convert_kernel(
    const float* __restrict__ Wqkv, const float* __restrict__ Wo,
    const float* __restrict__ Wf1, const float* __restrict__ Wf2,
    unsigned int* __restrict__ wb) {
  const int p = blockIdx.x * 1024 + threadIdx.x;
  if (p >= WB_TOT) return;
  const float* src;
  int off;
  if (p < WB_WO) { src = Wqkv; off = p; }
  else if (p < WB_WF1) { src = Wo; off = p - WB_WO; }
  else if (p < WB_WF2) { src = Wf1; off = p - WB_WF1; }
  else { src = Wf2; off = p - WB_WF2; }
  const float2 v = ((const float2*)src)[off];
  wb[p] = f2b(v.x) | (f2b(v.y) << 16);
}

// ---------------- K1: prep = qkv GEMM (blocks 0..191) + sortrank (192..207)
__global__ __launch_bounds__(1024) void prep_kernel(
    const float* __restrict__ x, const unsigned short* __restrict__ WqkvB,
    const float* __restrict__ bqkv, const float* __restrict__ W1,
    const float* __restrict__ b1, float* __restrict__ kk,
    float2* __restrict__ qv2, float* __restrict__ t_sorted,
    int* __restrict__ idx_sorted) {
  __shared__ float xs[2][DIMX];
  __shared__ float red[2][2][768];  // 12 KB
  __shared__ float ts[HID];
  __shared__ int part[64][17];
  const int tid = threadIdx.x;
  if (blockIdx.x < 192) {
    const int r0 = blockIdx.x * 2;
    const int c = tid & 255;
    const int rr = (tid >> 8) & 1;
    const int kc = tid >> 9;
    if (tid < 512)
      xs[tid >> 8][tid & 255] = x[(r0 + (tid >> 8)) * DIMX + (tid & 255)];
    __syncthreads();
    float a0 = 0.f, a1 = 0.f, a2 = 0.f;
    const int k0 = kc * 128;
#pragma unroll 4
    for (int i = 0; i < 128; ++i) {
      const int k = k0 + i;
      const float xv = xs[rr][k];
      a0 += xv * __uint_as_float(((unsigned int)WqkvB[k * 768 + c]) << 16);
      a1 += xv * __uint_as_float(((unsigned int)WqkvB[k * 768 + 256 + c]) << 16);
      a2 += xv * __uint_as_float(((unsigned int)WqkvB[k * 768 + 512 + c]) << 16);
    }
    red[kc][rr][c] = a0;
    red[kc][rr][256 + c] = a1;
    red[kc][rr][512 + c] = a2;
    __syncthreads();
    if (kc == 0) {
      const int row = r0 + rr;
      kk[row * DIMX + c] = red[0][rr][256 + c] + red[1][rr][256 + c] + bqkv[256 + c];
      const float q = red[0][rr][c] + red[1][rr][c] + bqkv[c];
      const float v = red[0][rr][512 + c] + red[1][rr][512 + c] + bqkv[512 + c];
      qv2[row * DIMX + c] = make_float2(q, v);
    }
  } else {
    const int bk = blockIdx.x - 192;
    {
      const float w = W1[tid];
      ts[tid] = (w != 0.f) ? (-b1[tid] / w) : INFINITY;
    }
    __syncthreads();
    const int hl = tid >> 4;
    const int ck = tid & 15;
    const int h = bk * 64 + hl;
    const float t = ts[h];
    int cnt = 0;
    const int r0 = ck * 64;
#pragma unroll 4
    for (int rr = 0; rr < 64; ++rr) {
      const int r = r0 + rr;
      const float tv = ts[r];
      cnt += ((tv < t) || (tv == t && r < h)) ? 1 : 0;
    }
    part[hl][ck] = cnt;
    __syncthreads();
    if (ck == 0) {
      int rank = 0;
#pragma unroll
      for (int u = 0; u < 16; ++u) rank += part[hl][u];
      t_sorted[rank] = t;
      idx_sorted[rank] = h;
    }
  }
}

// ------- K2: baseline + deltas + wave-shuffle inclusive scan -> SC table ----
__global__ __launch_bounds__(1024) void scan_kernel(
    const float* __restrict__ W1, const float* __restrict__ b1,
    const float* __restrict__ W2, const float* __restrict__ b2,
    const int* __restrict__ idx_sorted, float2* __restrict__ SC) {
  const int c = blockIdx.x;
  const int tid = threadIdx.x;
  const int lane = tid & 63;
  const int wid = tid >> 6;
  __shared__ float sW1[HID];
  __shared__ float sb1[HID];
  __shared__ int sidx[HID];
  __shared__ float bws[16], bwc[16], tws[16], twc[16];

  const float w = W1[tid];
  const float b1s = b1[tid];
  sW1[tid] = w;
  sb1[tid] = b1s;
  sidx[tid] = idx_sorted[tid];

  float bs = 0.f, bc = 0.f;
  {
    const float w2v = W2[tid * DIMX + c];
    if (w < 0.f) {
      bs = w * w2v;
      bc = b1s * w2v;
    } else if (w == 0.f && b1s > 0.f) {
      bc = b1s * w2v;
    }
  }
  for (int off = 32; off > 0; off >>= 1) {
    bs += __shfl_down(bs, off);
    bc += __shfl_down(bc, off);
  }
  __syncthreads();

  float vS, vC;
  {
    const int hh = sidx[tid];
    const float w1v = sW1[hh];
    const float sign = (w1v > 0.f) ? 1.f : -1.f;
    const float coefS = (w1v == 0.f) ? 0.f : sign * w1v;
    const float coefC = (w1v == 0.f) ? 0.f : sign * sb1[hh];
    const float w2v = W2[hh * DIMX + c];
    vS = coefS * w2v;
    vC = coefC * w2v;
  }
  for (int off = 1; off < 64; off <<= 1) {
    const float tS_ = __shfl_up(vS, off);
    const float tC_ = __shfl_up(vC, off);
    if (lane >= off) {
      vS += tS_;
      vC += tC_;
    }
  }
  if (lane == 0) {
    bws[wid] = bs;
    bwc[wid] = bc;
  }
  if (lane == 63) {
    tws[wid] = vS;
    twc[wid] = vC;
  }
  __syncthreads();
  float S0 = 0.f, C0 = 0.f, offS = 0.f, offC = 0.f;
#pragma unroll
  for (int u = 0; u < 16; ++u) {
    S0 += bws[u];
    C0 += bwc[u];
    if (u < wid) {
      offS += tws[u];
      offC += twc[u];
    }
  }
  C0 += b2[c];
  SC[(tid + 1) * DIMX + c] = make_float2(S0 + offS + vS, C0 + offC + vC);
  if (tid == 0) SC[c] = make_float2(S0, C0);
}

// ------- K3: fused distance-attention, 4-way j-split, no-max softmax -------
__global__ __launch_bounds__(1024) void attn_kernel(
    const float* __restrict__ pos, const int* __restrict__ mask,
    const float* __restrict__ kk, const float2* __restrict__ qv2,
    const float* __restrict__ t_sorted, const float2* __restrict__ SC,
    float* __restrict__ att) {
  __shared__ float tS[HID];
  __shared__ float posB[NN][3];
  __shared__ int maskB[NN];
  __shared__ float dJ[NN];
  __shared__ float decJ[NN];
  __shared__ int segJ[NN];
  __shared__ int pmJ[NN];
  __shared__ float sl[4][DIMX];
  __shared__ float so[4][DIMX];

  const int r = blockIdx.x;
  const int b = r / NN;
  const int i = r % NN;
  const int tid = threadIdx.x;
  const int c = tid & 255;
  const int jq = tid >> 8;

  tS[tid] = t_sorted[tid];
  if (tid < NN) {
    posB[tid][0] = pos[(b * NN + tid) * 3 + 0];
    posB[tid][1] = pos[(b * NN + tid) * 3 + 1];
    posB[tid][2] = pos[(b * NN + tid) * 3 + 2];
    maskB[tid] = mask[b * NN + tid];
  }
  __syncthreads();

  if (tid < NN) {
    const int j = tid;
    const float dx = posB[j][0] - posB[i][0];
    const float dy = posB[j][1] - posB[i][1];
    const float dz = posB[j][2] - posB[i][2];
    const float sq = dx * dx + dy * dy + dz * dz;
    const float d = (sq > 0.f) ? sqrtf(sq) : 0.f;
    dJ[j] = d;
    decJ[j] = __expf(-sq * 0.1f);
    int lo = 0, hi = HID;
    while (lo < hi) {
      const int mid = (lo + hi) >> 1;
      if (tS[mid] <= d) lo = mid + 1;
      else hi = mid;
    }
    segJ[j] = lo;
    pmJ[j] = maskB[i] && maskB[j];
  }
  __syncthreads();

  const float kc_ = kk[(b * NN + i) * DIMX + c];
  float l = 0.f, o = 0.f;
  const int j0 = jq * 48;
#pragma unroll 4
  for (int jj = 0; jj < 48; ++jj) {
    const int j = j0 + jj;
    const int seg = segJ[j];
    const float2 sc = SC[seg * DIMX + c];
    const float de = sc.y + dJ[j] * sc.x;
    const float2 qv = qv2[(b * NN + j) * DIMX + c];
    const float sval = decJ[j] * (kc_ + de) * (qv.x * SCALING);
    const float p = pmJ[j] ? 0.f : __expf(sval);
    l += p;
    o += p * qv.y;
  }
  sl[jq][c] = l;
  so[jq][c] = o;
  __syncthreads();
  if (tid < DIMX) {
    const float lt = sl[0][tid] + sl[1][tid] + sl[2][tid] + sl[3][tid];
    const float ot = so[0][tid] + so[1][tid] + so[2][tid] + so[3][tid];
    att[r * DIMX + tid] = ot / lt;
  }
}

// ------- K4: fused tail, bf16 weights, in-wave k-split + shuffle reduce ----
// 2 rows/block, 192 blocks. LDS ~14 KB.
__global__ __launch_bounds__(1024) void tail_kernel(
    const float* __restrict__ att, const float* __restrict__ x,
    const uint2* __restrict__ WoB, const float* __restrict__ bo,
    const float* __restrict__ ln1g, const float* __restrict__ ln1b,
    const uint2* __restrict__ Wf1B, const float* __restrict__ bf1,
    const uint2* __restrict__ Wf2B, const float* __restrict__ bf2,
    const float* __restrict__ ln2g, const float* __restrict__ ln2b,
    float* __restrict__ out) {
  __shared__ float2 attsT[DIMX];   // [k] -> (row0,row1)
  __shared__ float2 x1sT[DIMX];
  __shared__ float2 hidsT[HID];
  __shared__ float2 tT[DIMX];
  __shared__ float lr1[16], lr2[16];
  const int r0 = blockIdx.x * 2;
  const int tid = threadIdx.x;
  const int rr = tid >> 8;   // 0..3, valid rows 0..1
  const int c = tid & 255;
  const int w = tid >> 6;    // wave 0..15
  const int l = tid & 63;

  float xr = 0.f;
  if (rr < 2) {
    ((float*)&attsT[c])[rr] = att[(r0 + rr) * DIMX + c];
    xr = x[(r0 + rr) * DIMX + c];
  }
  __syncthreads();

  // ---- proj: wave w -> cols [w*16, w*16+16); lane: cg=l&3 (float4 col), kc=l>>2
  {
    const int cg = l & 3, kc = l >> 2;
    const int cb = w * 16 + cg * 4;
    float acc[2][4] = {{0.f, 0.f, 0.f, 0.f}, {0.f, 0.f, 0.f, 0.f}};
#pragma unroll
    for (int s = 0; s < 16; ++s) {
      const int k = kc * 16 + ((s + kc) & 15);   // stagger: no LDS bank pileup
      const uint2 wu = WoB[k * 64 + w * 4 + cg];
      const float wt[4] = {__uint_as_float(wu.x << 16),
                           __uint_as_float(wu.x & 0xffff0000u),
                           __uint_as_float(wu.y << 16),
                           __uint_as_float(wu.y & 0xffff0000u)};
      const float2 av = attsT[k];
#pragma unroll
      for (int j = 0; j < 4; ++j) {
        acc[0][j] += av.x * wt[j];
        acc[1][j] += av.y * wt[j];
      }
    }
#pragma unroll
    for (int m = 4; m <= 32; m <<= 1)
#pragma unroll
      for (int rj = 0; rj < 8; ++rj)
        acc[rj >> 2][rj & 3] += __shfl_xor(acc[rj >> 2][rj & 3], m);
    if (l < 4) {
#pragma unroll
      for (int j = 0; j < 4; ++j) tT[cb + j] = make_float2(acc[0][j], acc[1][j]);
    }
  }
  __syncthreads();

  // ---- LN1 ----
  float t1 = 0.f;
  if (rr < 2) t1 = ((float*)&tT[c])[rr] + xr + bo[c];
  {
    float s1 = t1, s2 = t1 * t1;
#pragma unroll
    for (int m = 32; m > 0; m >>= 1) {
      s1 += __shfl_down(s1, m);
      s2 += __shfl_down(s2, m);
    }
    if (l == 0) { lr1[w] = s1; lr2[w] = s2; }
  }
  __syncthreads();
  float x1v = 0.f;
  if (rr < 2) {
    const int base = rr * 4;
    const float S1 = lr1[base] + lr1[base + 1] + lr1[base + 2] + lr1[base + 3];
    const float S2 = lr2[base] + lr2[base + 1] + lr2[base + 2] + lr2[base + 3];
    const float mu = S1 * (1.f / DIMX);
    const float var = S2 * (1.f / DIMX) - mu * mu;
    x1v = (t1 - mu) * rsqrtf(var + EPS) * ln1g[c] + ln1b[c];
    ((float*)&x1sT[c])[rr] = x1v;
  }
  __syncthreads();

  // ---- FFN1: wave w -> hidden [w*64, w*64+64); lane: hg=l&15, kc=l>>4 ----
  {
    const int hg = l & 15, kc = l >> 4;
    const int hb = w * 64 + hg * 4;
    float acc[2][4] = {{0.f, 0.f, 0.f, 0.f}, {0.f, 0.f, 0.f, 0.f}};
#pragma unroll 8
    for (int s = 0; s < 64; ++s) {
      const int k = kc * 64 + ((s + kc * 2) & 63);
      const uint2 wu = Wf1B[k * 256 + w * 16 + hg];
      const float wt[4] = {__uint_as_float(wu.x << 16),
                           __uint_as_float(wu.x & 0xffff0000u),
                           __uint_as_float(wu.y << 16),
                           __uint_as_float(wu.y & 0xffff0000u)};
      const float2 xv = x1sT[k];
#pragma unroll
      for (int j = 0; j < 4; ++j) {
        acc[0][j] += xv.x * wt[j];
        acc[1][j] += xv.y * wt[j];
      }
    }
#pragma unroll
    for (int m = 16; m <= 32; m <<= 1)
#pragma unroll
      for (int rj = 0; rj < 8; ++rj)
        acc[rj >> 2][rj & 3] += __shfl_xor(acc[rj >> 2][rj & 3], m);
    if (l < 16) {
      const float4 bv = ((const float4*)bf1)[hb >> 2];
      const float ba[4] = {bv.x, bv.y, bv.z, bv.w};
#pragma unroll
      for (int j = 0; j < 4; ++j)
        hidsT[hb + j] = make_float2(fmaxf(acc[0][j] + ba[j], 0.f),
                                    fmaxf(acc[1][j] + ba[j], 0.f));
    }
  }
  __syncthreads();

  // ---- FFN2: wave w -> cols [w*16, w*16+16); lane: cg=l&3, kc=l>>2 (64k) --
  {
    const int cg = l & 3, kc = l >> 2;
    const int cb = w * 16 + cg * 4;
    float acc[2][4] = {{0.f, 0.f, 0.f, 0.f}, {0.f, 0.f, 0.f, 0.f}};
#pragma unroll 8
    for (int s = 0; s < 64; ++s) {
      const int k = kc * 64 + ((s + kc) & 63);
      const uint2 wu = Wf2B[k * 64 + w * 4 + cg];
      const float wt[4] = {__uint_as_float(wu.x << 16),
                           __uint_as_float(wu.x & 0xffff0000u),
                           __uint_as_float(wu.y << 16),
                           __uint_as_float(wu.y & 0xffff0000u)};
      const float2 hv = hidsT[k];
#pragma unroll
      for (int j = 0; j < 4; ++j) {
        acc[0][j] += hv.x * wt[j];
        acc[1][j] += hv.y * wt[j];
      }
    }
#pragma unroll
    for (int m = 4; m <= 32; m <<= 1)
#pragma unroll
      for (int rj = 0; rj < 8; ++rj)
        acc[rj >> 2][rj & 3] += __shfl_xor(acc[rj >> 2][rj & 3], m);
    if (l < 4) {
#pragma unroll
      for (int j = 0; j < 4; ++j) tT[cb + j] = make_float2(acc[0][j], acc[1][j]);
    }
  }
  __syncthreads();

  // ---- LN2 ----
  float t2 = 0.f;
  if (rr < 2) t2 = ((float*)&tT[c])[rr] + x1v + bf2[c];
  {
    float s1 = t2, s2 = t2 * t2;
#pragma unroll
    for (int m = 32; m > 0; m >>= 1) {
      s1 += __shfl_down(s1, m);
      s2 += __shfl_down(s2, m);
    }
    if (l == 0) { lr1[w] = s1; lr2[w] = s2; }
  }
  __syncthreads();
  if (rr < 2) {
    const int base = rr * 4;
    const float S1 = lr1[base] + lr1[base + 1] + lr1[base + 2] + lr1[base + 3];
    const float S2 = lr2[base] + lr2[base + 1] + lr2[base + 2] + lr2[base + 3];
    const float mu = S1 * (1.f / DIMX);
    const float var = S2 * (1.f / DIMX) - mu * mu;
    out[(r0 + rr) * DIMX + c] = (t2 - mu) * rsqrtf(var + EPS) * ln2g[c] + ln2b[c];
  }
}

extern "C" void kernel_launch(void* const* d_in, const int* in_sizes, int n_in,
                              void* d_out, int out_size, void* d_ws,
                              size_t ws_size, hipStream_t stream) {
  const float* x = (const float*)d_in[0];
  const float* pos = (const float*)d_in[1];
  const int* mask = (const int*)d_in[2];
  const float* Wqkv = (const float*)d_in[3];
  const float* bqkv = (const float*)d_in[4];
  const float* W1 = (const float*)d_in[5];
  const float* b1 = (const float*)d_in[6];
  const float* W2 = (const float*)d_in[7];
  const float* b2 = (const float*)d_in[8];
  const float* Wo = (const float*)d_in[9];
  const float* bo = (const float*)d_in[10];
  const float* ln1g = (const float*)d_in[11];
  const float* ln1b = (const float*)d_in[12];
  const float* Wf1 = (const float*)d_in[13];
  const float* bf1 = (const float*)d_in[14];
  const float* Wf2 = (const float*)d_in[15];
  const float* bf2 = (const float*)d_in[16];
  const float* ln2g = (const float*)d_in[17];
  const float* ln2b = (const float*)d_in[18];

  float* ws = (float*)d_ws;
  float* kk = ws + OFF_KK;
  float2* qv2 = (float2*)(ws + OFF_QV);
  float* t_sorted = ws + OFF_TSORT;
  int* idx_sorted = (int*)(ws + OFF_IDX);
  float2* SC = (float2*)(ws + OFF_SC);
  float* att = ws + OFF_ATT;
  unsigned int* wb = (unsigned int*)(ws + OFF_WB);
  float* outp = (float*)d_out;

  hipLaunchKernelGGL(convert_kernel, dim3(384), dim3(1024), 0, stream, Wqkv,
                     Wo, Wf1, Wf2, wb);
  hipLaunchKernelGGL(prep_kernel, dim3(208), dim3(1024), 0, stream, x,
                     (const unsigned short*)(wb + WB_QKV), bqkv, W1, b1, kk,
                     qv2, t_sorted, idx_sorted);
  hipLaunchKernelGGL(scan_kernel, dim3(DIMX), dim3(1024), 0, stream, W1, b1,
                     W2, b2, idx_sorted, SC);
  hipLaunchKernelGGL(attn_kernel, dim3(NROWS), dim3(1024), 0, stream, pos,
                     mask, kk, qv2, t_sorted, SC, att);
  hipLaunchKernelGGL(tail_kernel, dim3(NROWS / 2), dim3(1024), 0, stream, att,
                     x, (const uint2*)(wb + WB_WO), bo, ln1g, ln1b,
                     (const uint2*)(wb + WB_WF1), bf1,
                     (const uint2*)(wb + WB_WF2), bf2, ln2g, ln2b, outp);
}

// Round 7
// 76.710 us; speedup vs baseline: 1.5713x; 1.5713x over previous
//
#include <hip/hip_runtime.h>
#include <math.h>

#define NB 2
#define NN 192
#define DIMX 256
#define HID 1024
#define NROWS (NB * NN)            // 384
#define SCALING 0.17677669529663687f  // 1/sqrt(32)
#define EPS 1e-5f

// workspace layout (float/uint offsets)
#define OFF_KK    0                               // fp32 k-part, NROWS*256
#define OFF_QVP   (OFF_KK + NROWS * DIMX)         // packed (q*s,v) bf16 uints
#define OFF_TSORT (OFF_QVP + NROWS * DIMX)        // 1024
#define OFF_IDX   (OFF_TSORT + HID)               // 1024 ints
#define OFF_SCP   (OFF_IDX + HID)                 // packed (S,C) uints (HID+1)*256
#define OFF_ATT   (OFF_SCP + (HID + 1) * DIMX)
#define OFF_WB    (OFF_ATT + NROWS * DIMX)        // packed bf16 weights
// bf16 weight regions in uints (2 weights per uint):
#define WB_WO  0        // 32768  (256x256)
#define WB_WF1 32768    // 131072 (256x1024)
#define WB_WF2 163840   // 131072 (1024x256)
#define WB_TOT 294912
// end = OFF_WB + 294912 = 854,272 floats ≈ 3.4 MB

__device__ inline unsigned int f2b(float f) {
  const unsigned int u = __float_as_uint(f);
  return (u + 0x7fffu + ((u >> 16) & 1u)) >> 16;
}
__device__ inline float blo(unsigned int u) {
  return __uint_as_float(u << 16);
}
__device__ inline float bhi(unsigned int u) {
  return __uint_as_float(u & 0xffff0000u);
}

// ---------------- K0: convert Wo/Wf1/Wf2 to packed bf16 ----------------
__global__ __launch_bounds__(1024) void convert_kernel(
    const float* __restrict__ Wo, const float* __restrict__ Wf1,
    const float* __restrict__ Wf2, unsigned int* __restrict__ wb) {
  const int p = blockIdx.x * 1024 + threadIdx.x;
  if (p >= WB_TOT) return;
  const float* src;
  int off;
  if (p < WB_WF1) { src = Wo; off = p; }
  else if (p < WB_WF2) { src = Wf1; off = p - WB_WF1; }
  else { src = Wf2; off = p - WB_WF2; }
  const float2 v = ((const float2*)src)[off];
  wb[p] = f2b(v.x) | (f2b(v.y) << 16);
}

// ---------------- K1: prep = qkv GEMM (blocks 0..191) + sortrank (192..207)
__global__ __launch_bounds__(1024) void prep_kernel(
    const float* __restrict__ x, const float* __restrict__ Wqkv,
    const float* __restrict__ bqkv, const float* __restrict__ W1,
    const float* __restrict__ b1, float* __restrict__ kk,
    unsigned int* __restrict__ qvp, float* __restrict__ t_sorted,
    int* __restrict__ idx_sorted) {
  __shared__ float xs[2][DIMX];
  __shared__ float red[2][2][768];  // 12 KB
  __shared__ float ts[HID];
  __shared__ int part[64][17];
  const int tid = threadIdx.x;
  if (blockIdx.x < 192) {
    const int r0 = blockIdx.x * 2;
    const int c = tid & 255;
    const int rr = (tid >> 8) & 1;
    const int kc = tid >> 9;
    if (tid < 512)
      xs[tid >> 8][tid & 255] = x[(r0 + (tid >> 8)) * DIMX + (tid & 255)];
    __syncthreads();
    float a0 = 0.f, a1 = 0.f, a2 = 0.f;
    const int k0 = kc * 128;
#pragma unroll 4
    for (int i = 0; i < 128; ++i) {
      const int k = k0 + i;
      const float xv = xs[rr][k];
      a0 += xv * Wqkv[k * 768 + c];
      a1 += xv * Wqkv[k * 768 + 256 + c];
      a2 += xv * Wqkv[k * 768 + 512 + c];
    }
    red[kc][rr][c] = a0;
    red[kc][rr][256 + c] = a1;
    red[kc][rr][512 + c] = a2;
    __syncthreads();
    if (kc == 0) {
      const int row = r0 + rr;
      kk[row * DIMX + c] = red[0][rr][256 + c] + red[1][rr][256 + c] + bqkv[256 + c];
      const float q = red[0][rr][c] + red[1][rr][c] + bqkv[c];
      const float v = red[0][rr][512 + c] + red[1][rr][512 + c] + bqkv[512 + c];
      qvp[row * DIMX + c] = f2b(q * SCALING) | (f2b(v) << 16);
    }
  } else {
    const int bk = blockIdx.x - 192;
    {
      const float w = W1[tid];
      ts[tid] = (w != 0.f) ? (-b1[tid] / w) : INFINITY;
    }
    __syncthreads();
    const int hl = tid >> 4;
    const int ck = tid & 15;
    const int h = bk * 64 + hl;
    const float t = ts[h];
    int cnt = 0;
    const int r0 = ck * 64;
#pragma unroll 4
    for (int rr = 0; rr < 64; ++rr) {
      const int r = r0 + rr;
      const float tv = ts[r];
      cnt += ((tv < t) || (tv == t && r < h)) ? 1 : 0;
    }
    part[hl][ck] = cnt;
    __syncthreads();
    if (ck == 0) {
      int rank = 0;
#pragma unroll
      for (int u = 0; u < 16; ++u) rank += part[hl][u];
      t_sorted[rank] = t;
      idx_sorted[rank] = h;
    }
  }
}

// ------- K2: baseline + deltas + wave-shuffle inclusive scan -> SC packed --
__global__ __launch_bounds__(1024) void scan_kernel(
    const float* __restrict__ W1, const float* __restrict__ b1,
    const float* __restrict__ W2, const float* __restrict__ b2,
    const int* __restrict__ idx_sorted, unsigned int* __restrict__ SCp) {
  const int c = blockIdx.x;
  const int tid = threadIdx.x;
  const int lane = tid & 63;
  const int wid = tid >> 6;
  __shared__ float sW1[HID];
  __shared__ float sb1[HID];
  __shared__ int sidx[HID];
  __shared__ float bws[16], bwc[16], tws[16], twc[16];

  const float w = W1[tid];
  const float b1s = b1[tid];
  sW1[tid] = w;
  sb1[tid] = b1s;
  sidx[tid] = idx_sorted[tid];

  float bs = 0.f, bc = 0.f;
  {
    const float w2v = W2[tid * DIMX + c];
    if (w < 0.f) {
      bs = w * w2v;
      bc = b1s * w2v;
    } else if (w == 0.f && b1s > 0.f) {
      bc = b1s * w2v;
    }
  }
  for (int off = 32; off > 0; off >>= 1) {
    bs += __shfl_down(bs, off);
    bc += __shfl_down(bc, off);
  }
  __syncthreads();

  float vS, vC;
  {
    const int hh = sidx[tid];
    const float w1v = sW1[hh];
    const float sign = (w1v > 0.f) ? 1.f : -1.f;
    const float coefS = (w1v == 0.f) ? 0.f : sign * w1v;
    const float coefC = (w1v == 0.f) ? 0.f : sign * sb1[hh];
    const float w2v = W2[hh * DIMX + c];
    vS = coefS * w2v;
    vC = coefC * w2v;
  }
  for (int off = 1; off < 64; off <<= 1) {
    const float tS_ = __shfl_up(vS, off);
    const float tC_ = __shfl_up(vC, off);
    if (lane >= off) {
      vS += tS_;
      vC += tC_;
    }
  }
  if (lane == 0) {
    bws[wid] = bs;
    bwc[wid] = bc;
  }
  if (lane == 63) {
    tws[wid] = vS;
    twc[wid] = vC;
  }
  __syncthreads();
  float S0 = 0.f, C0 = 0.f, offS = 0.f, offC = 0.f;
#pragma unroll
  for (int u = 0; u < 16; ++u) {
    S0 += bws[u];
    C0 += bwc[u];
    if (u < wid) {
      offS += tws[u];
      offC += twc[u];
    }
  }
  C0 += b2[c];
  SCp[(tid + 1) * DIMX + c] = f2b(S0 + offS + vS) | (f2b(C0 + offC + vC) << 16);
  if (tid == 0) SCp[c] = f2b(S0) | (f2b(C0) << 16);
}

// ------- K3: fused distance-attention, packed bf16 SC/qv, no-max softmax ---
__global__ __launch_bounds__(1024) void attn_kernel(
    const float* __restrict__ pos, const int* __restrict__ mask,
    const float* __restrict__ kk, const unsigned int* __restrict__ qvp,
    const float* __restrict__ t_sorted, const unsigned int* __restrict__ SCp,
    float* __restrict__ att) {
  __shared__ float tS[HID];
  __shared__ float posB[NN][3];
  __shared__ int maskB[NN];
  __shared__ float dJ[NN];
  __shared__ float decJ[NN];
  __shared__ int segJ[NN];
  __shared__ int pmJ[NN];
  __shared__ float sl[4][DIMX];
  __shared__ float so[4][DIMX];

  const int r = blockIdx.x;
  const int b = r / NN;
  const int i = r % NN;
  const int tid = threadIdx.x;
  const int c = tid & 255;
  const int jq = tid >> 8;

  tS[tid] = t_sorted[tid];
  if (tid < NN) {
    posB[tid][0] = pos[(b * NN + tid) * 3 + 0];
    posB[tid][1] = pos[(b * NN + tid) * 3 + 1];
    posB[tid][2] = pos[(b * NN + tid) * 3 + 2];
    maskB[tid] = mask[b * NN + tid];
  }
  __syncthreads();

  if (tid < NN) {
    const int j = tid;
    const float dx = posB[j][0] - posB[i][0];
    const float dy = posB[j][1] - posB[i][1];
    const float dz = posB[j][2] - posB[i][2];
    const float sq = dx * dx + dy * dy + dz * dz;
    const float d = (sq > 0.f) ? sqrtf(sq) : 0.f;
    dJ[j] = d;
    decJ[j] = __expf(-sq * 0.1f);
    int lo = 0, hi = HID;
    while (lo < hi) {
      const int mid = (lo + hi) >> 1;
      if (tS[mid] <= d) lo = mid + 1;
      else hi = mid;
    }
    segJ[j] = lo;
    pmJ[j] = maskB[i] && maskB[j];
  }
  __syncthreads();

  const float kc_ = kk[(b * NN + i) * DIMX + c];
  float l = 0.f, o = 0.f;
  const int j0 = jq * 48;
#pragma unroll 4
  for (int jj = 0; jj < 48; ++jj) {
    const int j = j0 + jj;
    const int seg = segJ[j];
    const unsigned int scu = SCp[seg * DIMX + c];
    const float de = fmaf(dJ[j], blo(scu), bhi(scu));
    const unsigned int qvu = qvp[(b * NN + j) * DIMX + c];
    const float sval = decJ[j] * (kc_ + de) * blo(qvu);
    const float p = pmJ[j] ? 0.f : __expf(sval);
    l += p;
    o += p * bhi(qvu);
  }
  sl[jq][c] = l;
  so[jq][c] = o;
  __syncthreads();
  if (tid < DIMX) {
    const float lt = sl[0][tid] + sl[1][tid] + sl[2][tid] + sl[3][tid];
    const float ot = so[0][tid] + so[1][tid] + so[2][tid] + so[3][tid];
    att[r * DIMX + tid] = ot / lt;
  }
}

// ------- K4: fused tail (R5 structure, bf16 uint2 weights, coalesced) ------
__global__ __launch_bounds__(1024) void tail_kernel(
    const float* __restrict__ att, const float* __restrict__ x,
    const uint2* __restrict__ WoB, const float* __restrict__ bo,
    const float* __restrict__ ln1g, const float* __restrict__ ln1b,
    const uint2* __restrict__ Wf1B, const float* __restrict__ bf1,
    const uint2* __restrict__ Wf2B, const float* __restrict__ bf2,
    const float* __restrict__ ln2g, const float* __restrict__ ln2b,
    float* __restrict__ out) {
  __shared__ float atts[4][DIMX];     // 4 KB
  __shared__ float x1sT[DIMX][4];     // 4 KB (transposed: [k][row])
  __shared__ float hidsT[HID][4];     // 16 KB (transposed: [t][row])
  __shared__ float4 red[16][4][64];   // 64 KB, reused across phases
  __shared__ float lr1[16], lr2[16];
  const int r0 = blockIdx.x * 4;
  const int tid = threadIdx.x;
  const int rr = tid >> 8;   // 0..3 row
  const int c = tid & 255;   // channel

  atts[rr][c] = att[(r0 + rr) * DIMX + c];
  const float xr = x[(r0 + rr) * DIMX + c];
  __syncthreads();

  // ---- proj: (rr, ks=(tid>>6)&3, c4=tid&63); lanes contiguous in c4 ----
  {
    const int ks = (tid >> 6) & 3;
    const int c4 = tid & 63;
    float a0 = 0.f, a1 = 0.f, a2 = 0.f, a3 = 0.f;
#pragma unroll 8
    for (int i = 0; i < 64; ++i) {
      const int k = ks * 64 + i;
      const uint2 wu = WoB[k * 64 + c4];
      const float av = atts[rr][k];
      a0 += av * blo(wu.x); a1 += av * bhi(wu.x);
      a2 += av * blo(wu.y); a3 += av * bhi(wu.y);
    }
    red[ks][rr][c4] = make_float4(a0, a1, a2, a3);
  }
  __syncthreads();
  float t1;
  {
    const int c4 = c >> 2, cm = c & 3;
    const float pv = ((const float*)&red[0][rr][c4])[cm] +
                     ((const float*)&red[1][rr][c4])[cm] +
                     ((const float*)&red[2][rr][c4])[cm] +
                     ((const float*)&red[3][rr][c4])[cm];
    t1 = pv + xr + bo[c];
  }
  // ---- LN1 ----
  {
    float s1 = t1, s2 = t1 * t1;
    for (int off = 32; off > 0; off >>= 1) {
      s1 += __shfl_down(s1, off);
      s2 += __shfl_down(s2, off);
    }
    if ((tid & 63) == 0) { lr1[tid >> 6] = s1; lr2[tid >> 6] = s2; }
  }
  __syncthreads();
  float x1;
  {
    const int base = rr * 4;
    const float S1 = lr1[base] + lr1[base + 1] + lr1[base + 2] + lr1[base + 3];
    const float S2 = lr2[base] + lr2[base + 1] + lr2[base + 2] + lr2[base + 3];
    const float mu = S1 * (1.f / DIMX);
    const float var = S2 * (1.f / DIMX) - mu * mu;
    x1 = (t1 - mu) * rsqrtf(var + EPS) * ln1g[c] + ln1b[c];
  }
  x1sT[c][rr] = x1;
  __syncthreads();

  // ---- FFN1: (ks=tid>>8, h4=tid&255); lanes contiguous in h4 ----
  {
    const int ks = tid >> 8;
    const int h4 = tid & 255;
    float4 h0 = {0.f,0.f,0.f,0.f}, h1 = {0.f,0.f,0.f,0.f};
    float4 h2 = {0.f,0.f,0.f,0.f}, h3 = {0.f,0.f,0.f,0.f};
#pragma unroll 4
    for (int i = 0; i < 64; ++i) {
      const int k = ks * 64 + i;
      const uint2 wu = Wf1B[k * 256 + h4];
      const float w0 = blo(wu.x), w1 = bhi(wu.x), w2 = blo(wu.y), w3 = bhi(wu.y);
      const float4 xv = *(const float4*)&x1sT[k][0];
      h0.x += xv.x * w0; h0.y += xv.x * w1; h0.z += xv.x * w2; h0.w += xv.x * w3;
      h1.x += xv.y * w0; h1.y += xv.y * w1; h1.z += xv.y * w2; h1.w += xv.y * w3;
      h2.x += xv.z * w0; h2.y += xv.z * w1; h2.z += xv.z * w2; h2.w += xv.z * w3;
      h3.x += xv.w * w0; h3.y += xv.w * w1; h3.z += xv.w * w2; h3.w += xv.w * w3;
    }
    float4 (*redF)[4][256] = (float4(*)[4][256])red;
    redF[ks][0][h4] = h0;
    redF[ks][1][h4] = h1;
    redF[ks][2][h4] = h2;
    redF[ks][3][h4] = h3;
  }
  __syncthreads();
  {
    const int hh = tid;
    const int h4 = hh >> 2, cm = hh & 3;
    const float bf = bf1[hh];
    float4 (*redF)[4][256] = (float4(*)[4][256])red;
#pragma unroll
    for (int r_ = 0; r_ < 4; ++r_) {
      const float v = ((const float*)&redF[0][r_][h4])[cm] +
                      ((const float*)&redF[1][r_][h4])[cm] +
                      ((const float*)&redF[2][r_][h4])[cm] +
                      ((const float*)&redF[3][r_][h4])[cm];
      hidsT[hh][r_] = fmaxf(v + bf, 0.f);
    }
  }
  __syncthreads();

  // ---- FFN2: (ks=tid>>6 (16), c4=tid&63); lanes contiguous in c4 ----
  {
    const int ks = tid >> 6;
    const int c4 = tid & 63;
    float4 a0 = {0.f,0.f,0.f,0.f}, a1 = {0.f,0.f,0.f,0.f};
    float4 a2 = {0.f,0.f,0.f,0.f}, a3 = {0.f,0.f,0.f,0.f};
#pragma unroll 4
    for (int i = 0; i < 64; ++i) {
      const int k = ks * 64 + i;
      const uint2 wu = Wf2B[k * 64 + c4];
      const float w0 = blo(wu.x), w1 = bhi(wu.x), w2 = blo(wu.y), w3 = bhi(wu.y);
      const float4 hv = *(const float4*)&hidsT[k][0];
      a0.x += hv.x * w0; a0.y += hv.x * w1; a0.z += hv.x * w2; a0.w += hv.x * w3;
      a1.x += hv.y * w0; a1.y += hv.y * w1; a1.z += hv.y * w2; a1.w += hv.y * w3;
      a2.x += hv.z * w0; a2.y += hv.z * w1; a2.z += hv.z * w2; a2.w += hv.z * w3;
      a3.x += hv.w * w0; a3.y += hv.w * w1; a3.z += hv.w * w2; a3.w += hv.w * w3;
    }
    red[ks][0][c4] = a0;
    red[ks][1][c4] = a1;
    red[ks][2][c4] = a2;
    red[ks][3][c4] = a3;
  }
  __syncthreads();
  float t2;
  {
    const int c4 = c >> 2, cm = c & 3;
    float pv = 0.f;
#pragma unroll
    for (int u = 0; u < 16; ++u) pv += ((const float*)&red[u][rr][c4])[cm];
    t2 = pv + x1 + bf2[c];
  }
  // ---- LN2 ----
  {
    float s1 = t2, s2 = t2 * t2;
    for (int off = 32; off > 0; off >>= 1) {
      s1 += __shfl_down(s1, off);
      s2 += __shfl_down(s2, off);
    }
    if ((tid & 63) == 0) { lr1[tid >> 6] = s1; lr2[tid >> 6] = s2; }
  }
  __syncthreads();
  {
    const int base = rr * 4;
    const float S1 = lr1[base] + lr1[base + 1] + lr1[base + 2] + lr1[base + 3];
    const float S2 = lr2[base] + lr2[base + 1] + lr2[base + 2] + lr2[base + 3];
    const float mu = S1 * (1.f / DIMX);
    const float var = S2 * (1.f / DIMX) - mu * mu;
    out[(r0 + rr) * DIMX + c] = (t2 - mu) * rsqrtf(var + EPS) * ln2g[c] + ln2b[c];
  }
}

extern "C" void kernel_launch(void* const* d_in, const int* in_sizes, int n_in,
                              void* d_out, int out_size, void* d_ws,
                              size_t ws_size, hipStream_t stream) {
  const float* x = (const float*)d_in[0];
  const float* pos = (const float*)d_in[1];
  const int* mask = (const int*)d_in[2];
  const float* Wqkv = (const float*)d_in[3];
  const float* bqkv = (const float*)d_in[4];
  const float* W1 = (const float*)d_in[5];
  const float* b1 = (const float*)d_in[6];
  const float* W2 = (const float*)d_in[7];
  const float* b2 = (const float*)d_in[8];
  const float* Wo = (const float*)d_in[9];
  const float* bo = (const float*)d_in[10];
  const float* ln1g = (const float*)d_in[11];
  const float* ln1b = (const float*)d_in[12];
  const float* Wf1 = (const float*)d_in[13];
  const float* bf1 = (const float*)d_in[14];
  const float* Wf2 = (const float*)d_in[15];
  const float* bf2 = (const float*)d_in[16];
  const float* ln2g = (const float*)d_in[17];
  const float* ln2b = (const float*)d_in[18];

  float* ws = (float*)d_ws;
  float* kk = ws + OFF_KK;
  unsigned int* qvp = (unsigned int*)(ws + OFF_QVP);
  float* t_sorted = ws + OFF_TSORT;
  int* idx_sorted = (int*)(ws + OFF_IDX);
  unsigned int* SCp = (unsigned int*)(ws + OFF_SCP);
  float* att = ws + OFF_ATT;
  unsigned int* wb = (unsigned int*)(ws + OFF_WB);
  float* outp = (float*)d_out;

  hipLaunchKernelGGL(convert_kernel, dim3(288), dim3(1024), 0, stream, Wo,
                     Wf1, Wf2, wb);
  hipLaunchKernelGGL(prep_kernel, dim3(208), dim3(1024), 0, stream, x, Wqkv,
                     bqkv, W1, b1, kk, qvp, t_sorted, idx_sorted);
  hipLaunchKernelGGL(scan_kernel, dim3(DIMX), dim3(1024), 0, stream, W1, b1,
                     W2, b2, idx_sorted, SCp);
  hipLaunchKernelGGL(attn_kernel, dim3(NROWS), dim3(1024), 0, stream, pos,
                     mask, kk, qvp, t_sorted, SCp, att);
  hipLaunchKernelGGL(tail_kernel, dim3(NROWS / 4), dim3(1024), 0, stream, att,
                     x, (const uint2*)(wb + WB_WO), bo, ln1g, ln1b,
                     (const uint2*)(wb + WB_WF1), bf1,
                     (const uint2*)(wb + WB_WF2), bf2, ln2g, ln2b, outp);
}

// Round 8
// 61.242 us; speedup vs baseline: 1.9682x; 1.2526x over previous
//
#include <hip/hip_runtime.h>
#include <math.h>

#define NB 2
#define NN 192
#define DIMX 256
#define HID 1024
#define NROWS (NB * NN)            // 384
#define SCALING 0.17677669529663687f  // 1/sqrt(32)
#define EPS 1e-5f

// workspace layout (float/uint offsets)
#define OFF_KK    0                               // fp32 k-part, NROWS*256
#define OFF_QVP   (OFF_KK + NROWS * DIMX)         // packed (q*s,v) bf16 uints
#define OFF_TSORT (OFF_QVP + NROWS * DIMX)        // 1024
#define OFF_IDX   (OFF_TSORT + HID)               // 1024 ints
#define OFF_SCP   (OFF_IDX + HID)                 // packed (S,C) uints (HID+1)*256
#define OFF_ATT   (OFF_SCP + (HID + 1) * DIMX)
#define OFF_WB    (OFF_ATT + NROWS * DIMX)        // packed bf16 weights
// bf16 weight regions in uints (2 weights per uint):
#define WB_WO  0        // 32768  (256x256)
#define WB_WF1 32768    // 131072 (256x1024)
#define WB_WF2 163840   // 131072 (1024x256)
#define WB_TOT 294912

__device__ inline unsigned int f2b(float f) {
  const unsigned int u = __float_as_uint(f);
  return (u + 0x7fffu + ((u >> 16) & 1u)) >> 16;
}
__device__ inline float blo(unsigned int u) {
  return __uint_as_float(u << 16);
}
__device__ inline float bhi(unsigned int u) {
  return __uint_as_float(u & 0xffff0000u);
}

// ---- K1: qkv GEMM (blocks 0..95, 4 rows) + sortrank (96..111) +
//          weight bf16 convert (112..399) ----
__global__ __launch_bounds__(1024) void prep_kernel(
    const float* __restrict__ x, const float* __restrict__ Wqkv,
    const float* __restrict__ bqkv, const float* __restrict__ W1,
    const float* __restrict__ b1, const float* __restrict__ Wo,
    const float* __restrict__ Wf1, const float* __restrict__ Wf2,
    float* __restrict__ kk, unsigned int* __restrict__ qvp,
    float* __restrict__ t_sorted, int* __restrict__ idx_sorted,
    unsigned int* __restrict__ wb) {
  __shared__ float xs[4][DIMX];       // 4 KB
  __shared__ float red[4][4][768];    // 48 KB
  __shared__ float ts[HID];           // 4 KB
  __shared__ int part[64][17];        // 4.3 KB
  const int tid = threadIdx.x;
  const int bx = blockIdx.x;
  if (bx < 96) {
    const int r0 = bx * 4;
    const int kc = tid >> 8;       // 4-way k split
    const int c = tid & 255;
    xs[tid >> 8][tid & 255] = x[(r0 + (tid >> 8)) * DIMX + (tid & 255)];
    __syncthreads();
    float acc[4][3];
#pragma unroll
    for (int rr = 0; rr < 4; ++rr)
      for (int u = 0; u < 3; ++u) acc[rr][u] = 0.f;
    const int k0 = kc * 64;
#pragma unroll 4
    for (int i = 0; i < 64; ++i) {
      const int k = k0 + i;
      const float w0 = Wqkv[k * 768 + c];
      const float w1 = Wqkv[k * 768 + 256 + c];
      const float w2 = Wqkv[k * 768 + 512 + c];
#pragma unroll
      for (int rr = 0; rr < 4; ++rr) {
        const float xv = xs[rr][k];
        acc[rr][0] += xv * w0;
        acc[rr][1] += xv * w1;
        acc[rr][2] += xv * w2;
      }
    }
#pragma unroll
    for (int rr = 0; rr < 4; ++rr) {
      red[kc][rr][c] = acc[rr][0];
      red[kc][rr][256 + c] = acc[rr][1];
      red[kc][rr][512 + c] = acc[rr][2];
    }
    __syncthreads();
    {
      const int rr = tid >> 8;
      const int row = r0 + rr;
      const float q = red[0][rr][c] + red[1][rr][c] + red[2][rr][c] +
                      red[3][rr][c] + bqkv[c];
      const float kkv = red[0][rr][256 + c] + red[1][rr][256 + c] +
                        red[2][rr][256 + c] + red[3][rr][256 + c] +
                        bqkv[256 + c];
      const float v = red[0][rr][512 + c] + red[1][rr][512 + c] +
                      red[2][rr][512 + c] + red[3][rr][512 + c] +
                      bqkv[512 + c];
      kk[row * DIMX + c] = kkv;
      qvp[row * DIMX + c] = f2b(q * SCALING) | (f2b(v) << 16);
    }
  } else if (bx < 112) {
    const int bk = bx - 96;
    {
      const float w = W1[tid];
      ts[tid] = (w != 0.f) ? (-b1[tid] / w) : INFINITY;
    }
    __syncthreads();
    const int hl = tid >> 4;
    const int ck = tid & 15;
    const int h = bk * 64 + hl;
    const float t = ts[h];
    int cnt = 0;
    const int r0 = ck * 64;
#pragma unroll 4
    for (int rr = 0; rr < 64; ++rr) {
      const int r = r0 + rr;
      const float tv = ts[r];
      cnt += ((tv < t) || (tv == t && r < h)) ? 1 : 0;
    }
    part[hl][ck] = cnt;
    __syncthreads();
    if (ck == 0) {
      int rank = 0;
#pragma unroll
      for (int u = 0; u < 16; ++u) rank += part[hl][u];
      t_sorted[rank] = t;
      idx_sorted[rank] = h;
    }
  } else {
    const int p = (bx - 112) * 1024 + tid;
    if (p < WB_TOT) {
      const float* src;
      int off;
      if (p < WB_WF1) { src = Wo; off = p; }
      else if (p < WB_WF2) { src = Wf1; off = p - WB_WF1; }
      else { src = Wf2; off = p - WB_WF2; }
      const float2 v = ((const float2*)src)[off];
      wb[p] = f2b(v.x) | (f2b(v.y) << 16);
    }
  }
}

// ------- K2: baseline + deltas + wave-shuffle inclusive scan -> SC packed --
__global__ __launch_bounds__(1024) void scan_kernel(
    const float* __restrict__ W1, const float* __restrict__ b1,
    const float* __restrict__ W2, const float* __restrict__ b2,
    const int* __restrict__ idx_sorted, unsigned int* __restrict__ SCp) {
  const int c = blockIdx.x;
  const int tid = threadIdx.x;
  const int lane = tid & 63;
  const int wid = tid >> 6;
  __shared__ float sW1[HID];
  __shared__ float sb1[HID];
  __shared__ int sidx[HID];
  __shared__ float bws[16], bwc[16], tws[16], twc[16];

  const float w = W1[tid];
  const float b1s = b1[tid];
  sW1[tid] = w;
  sb1[tid] = b1s;
  sidx[tid] = idx_sorted[tid];

  float bs = 0.f, bc = 0.f;
  {
    const float w2v = W2[tid * DIMX + c];
    if (w < 0.f) {
      bs = w * w2v;
      bc = b1s * w2v;
    } else if (w == 0.f && b1s > 0.f) {
      bc = b1s * w2v;
    }
  }
  for (int off = 32; off > 0; off >>= 1) {
    bs += __shfl_down(bs, off);
    bc += __shfl_down(bc, off);
  }
  __syncthreads();

  float vS, vC;
  {
    const int hh = sidx[tid];
    const float w1v = sW1[hh];
    const float sign = (w1v > 0.f) ? 1.f : -1.f;
    const float coefS = (w1v == 0.f) ? 0.f : sign * w1v;
    const float coefC = (w1v == 0.f) ? 0.f : sign * sb1[hh];
    const float w2v = W2[hh * DIMX + c];
    vS = coefS * w2v;
    vC = coefC * w2v;
  }
  for (int off = 1; off < 64; off <<= 1) {
    const float tS_ = __shfl_up(vS, off);
    const float tC_ = __shfl_up(vC, off);
    if (lane >= off) {
      vS += tS_;
      vC += tC_;
    }
  }
  if (lane == 0) {
    bws[wid] = bs;
    bwc[wid] = bc;
  }
  if (lane == 63) {
    tws[wid] = vS;
    twc[wid] = vC;
  }
  __syncthreads();
  float S0 = 0.f, C0 = 0.f, offS = 0.f, offC = 0.f;
#pragma unroll
  for (int u = 0; u < 16; ++u) {
    S0 += bws[u];
    C0 += bwc[u];
    if (u < wid) {
      offS += tws[u];
      offC += twc[u];
    }
  }
  C0 += b2[c];
  SCp[(tid + 1) * DIMX + c] = f2b(S0 + offS + vS) | (f2b(C0 + offC + vC) << 16);
  if (tid == 0) SCp[c] = f2b(S0) | (f2b(C0) << 16);
}

// ------- K3: fused distance-attention, packed bf16 SC/qv, no-max softmax ---
__global__ __launch_bounds__(1024) void attn_kernel(
    const float* __restrict__ pos, const int* __restrict__ mask,
    const float* __restrict__ kk, const unsigned int* __restrict__ qvp,
    const float* __restrict__ t_sorted, const unsigned int* __restrict__ SCp,
    float* __restrict__ att) {
  __shared__ float tS[HID];
  __shared__ float posB[NN][3];
  __shared__ int maskB[NN];
  __shared__ float dJ[NN];
  __shared__ float decJ[NN];
  __shared__ int segJ[NN];
  __shared__ int pmJ[NN];
  __shared__ float sl[4][DIMX];
  __shared__ float so[4][DIMX];

  const int r = blockIdx.x;
  const int b = r / NN;
  const int i = r % NN;
  const int tid = threadIdx.x;
  const int c = tid & 255;
  const int jq = tid >> 8;

  tS[tid] = t_sorted[tid];
  if (tid < NN) {
    posB[tid][0] = pos[(b * NN + tid) * 3 + 0];
    posB[tid][1] = pos[(b * NN + tid) * 3 + 1];
    posB[tid][2] = pos[(b * NN + tid) * 3 + 2];
    maskB[tid] = mask[b * NN + tid];
  }
  __syncthreads();

  if (tid < NN) {
    const int j = tid;
    const float dx = posB[j][0] - posB[i][0];
    const float dy = posB[j][1] - posB[i][1];
    const float dz = posB[j][2] - posB[i][2];
    const float sq = dx * dx + dy * dy + dz * dz;
    const float d = (sq > 0.f) ? sqrtf(sq) : 0.f;
    dJ[j] = d;
    decJ[j] = __expf(-sq * 0.1f);
    int lo = 0, hi = HID;
    while (lo < hi) {
      const int mid = (lo + hi) >> 1;
      if (tS[mid] <= d) lo = mid + 1;
      else hi = mid;
    }
    segJ[j] = lo;
    pmJ[j] = maskB[i] && maskB[j];
  }
  __syncthreads();

  const float kc_ = kk[(b * NN + i) * DIMX + c];
  float l = 0.f, o = 0.f;
  const int j0 = jq * 48;
#pragma unroll 4
  for (int jj = 0; jj < 48; ++jj) {
    const int j = j0 + jj;
    const int seg = segJ[j];
    const unsigned int scu = SCp[seg * DIMX + c];
    const float de = fmaf(dJ[j], blo(scu), bhi(scu));
    const unsigned int qvu = qvp[(b * NN + j) * DIMX + c];
    const float sval = decJ[j] * (kc_ + de) * blo(qvu);
    const float p = pmJ[j] ? 0.f : __expf(sval);
    l += p;
    o += p * bhi(qvu);
  }
  sl[jq][c] = l;
  so[jq][c] = o;
  __syncthreads();
  if (tid < DIMX) {
    const float lt = sl[0][tid] + sl[1][tid] + sl[2][tid] + sl[3][tid];
    const float ot = so[0][tid] + so[1][tid] + so[2][tid] + so[3][tid];
    att[r * DIMX + tid] = ot / lt;
  }
}

// ------- K4: fused tail, 2 rows/block (192 blocks), bf16 uint2 weights -----
__global__ __launch_bounds__(1024) void tail_kernel(
    const float* __restrict__ att, const float* __restrict__ x,
    const uint2* __restrict__ WoB, const float* __restrict__ bo,
    const float* __restrict__ ln1g, const float* __restrict__ ln1b,
    const uint2* __restrict__ Wf1B, const float* __restrict__ bf1,
    const uint2* __restrict__ Wf2B, const float* __restrict__ bf2,
    const float* __restrict__ ln2g, const float* __restrict__ ln2b,
    float* __restrict__ out) {
  __shared__ float atts[2][DIMX];      // 2 KB
  __shared__ float2 x1sT[DIMX];        // 2 KB  [k] -> (row0,row1)
  __shared__ float2 hidsT[HID];        // 8 KB
  __shared__ float4 red[16][2][64];    // 32 KB (reused across phases)
  __shared__ float lr1[8], lr2[8];
  const int r0 = blockIdx.x * 2;
  const int tid = threadIdx.x;
  const int rr = tid >> 8;   // 0..3 (rows valid 0..1)
  const int c = tid & 255;

  if (tid < 512) atts[rr][c] = att[(r0 + rr) * DIMX + c];
  __syncthreads();

  // ---- proj: ks = tid>>6 (16 k-chunks of 16), c4 = tid&63 ----
  {
    const int ks = tid >> 6, c4 = tid & 63;
    float4 a0 = {0.f, 0.f, 0.f, 0.f}, a1 = {0.f, 0.f, 0.f, 0.f};
#pragma unroll
    for (int i = 0; i < 16; ++i) {
      const int k = ks * 16 + i;
      const uint2 wu = WoB[k * 64 + c4];
      const float w0 = blo(wu.x), w1 = bhi(wu.x), w2 = blo(wu.y), w3 = bhi(wu.y);
      const float v0 = atts[0][k], v1 = atts[1][k];
      a0.x += v0 * w0; a0.y += v0 * w1; a0.z += v0 * w2; a0.w += v0 * w3;
      a1.x += v1 * w0; a1.y += v1 * w1; a1.z += v1 * w2; a1.w += v1 * w3;
    }
    red[ks][0][c4] = a0;
    red[ks][1][c4] = a1;
  }
  __syncthreads();
  float t1 = 0.f, x1v = 0.f;
  if (rr < 2) {
    const float xr = x[(r0 + rr) * DIMX + c];
    const int c4 = c >> 2, cm = c & 3;
    float pv = 0.f;
#pragma unroll
    for (int u = 0; u < 16; ++u) pv += ((const float*)&red[u][rr][c4])[cm];
    t1 = pv + xr + bo[c];
  }
  // ---- LN1 (rows in waves 0..7; waves 8..15 contribute nothing) ----
  {
    float s1 = t1, s2 = t1 * t1;
    for (int off = 32; off > 0; off >>= 1) {
      s1 += __shfl_down(s1, off);
      s2 += __shfl_down(s2, off);
    }
    if ((tid & 63) == 0 && tid < 512) { lr1[tid >> 6] = s1; lr2[tid >> 6] = s2; }
  }
  __syncthreads();
  if (rr < 2) {
    const int base = rr * 4;
    const float S1 = lr1[base] + lr1[base + 1] + lr1[base + 2] + lr1[base + 3];
    const float S2 = lr2[base] + lr2[base + 1] + lr2[base + 2] + lr2[base + 3];
    const float mu = S1 * (1.f / DIMX);
    const float var = S2 * (1.f / DIMX) - mu * mu;
    x1v = (t1 - mu) * rsqrtf(var + EPS) * ln1g[c] + ln1b[c];
    ((float*)&x1sT[c])[rr] = x1v;
  }
  __syncthreads();

  // ---- FFN1: ks = tid>>8 (4 k-chunks of 64), h4 = tid&255 ----
  {
    const int ks = tid >> 8, h4 = tid & 255;
    float4 h0 = {0.f, 0.f, 0.f, 0.f}, h1 = {0.f, 0.f, 0.f, 0.f};
#pragma unroll 4
    for (int i = 0; i < 64; ++i) {
      const int k = ks * 64 + i;
      const uint2 wu = Wf1B[k * 256 + h4];
      const float w0 = blo(wu.x), w1 = bhi(wu.x), w2 = blo(wu.y), w3 = bhi(wu.y);
      const float2 xv = x1sT[k];
      h0.x += xv.x * w0; h0.y += xv.x * w1; h0.z += xv.x * w2; h0.w += xv.x * w3;
      h1.x += xv.y * w0; h1.y += xv.y * w1; h1.z += xv.y * w2; h1.w += xv.y * w3;
    }
    float4 (*redF)[2][256] = (float4(*)[2][256])red;
    redF[ks][0][h4] = h0;
    redF[ks][1][h4] = h1;
  }
  __syncthreads();
  {
    const int hh = tid;
    const int h4 = hh >> 2, cm = hh & 3;
    const float bf = bf1[hh];
    float4 (*redF)[2][256] = (float4(*)[2][256])red;
    const float v0 = ((const float*)&redF[0][0][h4])[cm] +
                     ((const float*)&redF[1][0][h4])[cm] +
                     ((const float*)&redF[2][0][h4])[cm] +
                     ((const float*)&redF[3][0][h4])[cm];
    const float v1 = ((const float*)&redF[0][1][h4])[cm] +
                     ((const float*)&redF[1][1][h4])[cm] +
                     ((const float*)&redF[2][1][h4])[cm] +
                     ((const float*)&redF[3][1][h4])[cm];
    __syncthreads();  // all reads of redF done before FFN2 overwrites red
    hidsT[hh] = make_float2(fmaxf(v0 + bf, 0.f), fmaxf(v1 + bf, 0.f));
  }
  __syncthreads();

  // ---- FFN2: ks = tid>>6 (16 k-chunks of 64), c4 = tid&63 ----
  {
    const int ks = tid >> 6, c4 = tid & 63;
    float4 a0 = {0.f, 0.f, 0.f, 0.f}, a1 = {0.f, 0.f, 0.f, 0.f};
#pragma unroll 4
    for (int i = 0; i < 64; ++i) {
      const int k = ks * 64 + i;
      const uint2 wu = Wf2B[k * 64 + c4];
      const float w0 = blo(wu.x), w1 = bhi(wu.x), w2 = blo(wu.y), w3 = bhi(wu.y);
      const float2 hv = hidsT[k];
      a0.x += hv.x * w0; a0.y += hv.x * w1; a0.z += hv.x * w2; a0.w += hv.x * w3;
      a1.x += hv.y * w0; a1.y += hv.y * w1; a1.z += hv.y * w2; a1.w += hv.y * w3;
    }
    red[ks][0][c4] = a0;
    red[ks][1][c4] = a1;
  }
  __syncthreads();
  float t2 = 0.f;
  if (rr < 2) {
    const int c4 = c >> 2, cm = c & 3;
    float pv = 0.f;
#pragma unroll
    for (int u = 0; u < 16; ++u) pv += ((const float*)&red[u][rr][c4])[cm];
    t2 = pv + x1v + bf2[c];
  }
  // ---- LN2 ----
  {
    float s1 = t2, s2 = t2 * t2;
    for (int off = 32; off > 0; off >>= 1) {
      s1 += __shfl_down(s1, off);
      s2 += __shfl_down(s2, off);
    }
    if ((tid & 63) == 0 && tid < 512) { lr1[tid >> 6] = s1; lr2[tid >> 6] = s2; }
  }
  __syncthreads();
  if (rr < 2) {
    const int base = rr * 4;
    const float S1 = lr1[base] + lr1[base + 1] + lr1[base + 2] + lr1[base + 3];
    const float S2 = lr2[base] + lr2[base + 1] + lr2[base + 2] + lr2[base + 3];
    const float mu = S1 * (1.f / DIMX);
    const float var = S2 * (1.f / DIMX) - mu * mu;
    out[(r0 + rr) * DIMX + c] = (t2 - mu) * rsqrtf(var + EPS) * ln2g[c] + ln2b[c];
  }
}

extern "C" void kernel_launch(void* const* d_in, const int* in_sizes, int n_in,
                              void* d_out, int out_size, void* d_ws,
                              size_t ws_size, hipStream_t stream) {
  const float* x = (const float*)d_in[0];
  const float* pos = (const float*)d_in[1];
  const int* mask = (const int*)d_in[2];
  const float* Wqkv = (const float*)d_in[3];
  const float* bqkv = (const float*)d_in[4];
  const float* W1 = (const float*)d_in[5];
  const float* b1 = (const float*)d_in[6];
  const float* W2 = (const float*)d_in[7];
  const float* b2 = (const float*)d_in[8];
  const float* Wo = (const float*)d_in[9];
  const float* bo = (const float*)d_in[10];
  const float* ln1g = (const float*)d_in[11];
  const float* ln1b = (const float*)d_in[12];
  const float* Wf1 = (const float*)d_in[13];
  const float* bf1 = (const float*)d_in[14];
  const float* Wf2 = (const float*)d_in[15];
  const float* bf2 = (const float*)d_in[16];
  const float* ln2g = (const float*)d_in[17];
  const float* ln2b = (const float*)d_in[18];

  float* ws = (float*)d_ws;
  float* kk = ws + OFF_KK;
  unsigned int* qvp = (unsigned int*)(ws + OFF_QVP);
  float* t_sorted = ws + OFF_TSORT;
  int* idx_sorted = (int*)(ws + OFF_IDX);
  unsigned int* SCp = (unsigned int*)(ws + OFF_SCP);
  float* att = ws + OFF_ATT;
  unsigned int* wb = (unsigned int*)(ws + OFF_WB);
  float* outp = (float*)d_out;

  hipLaunchKernelGGL(prep_kernel, dim3(400), dim3(1024), 0, stream, x, Wqkv,
                     bqkv, W1, b1, Wo, Wf1, Wf2, kk, qvp, t_sorted, idx_sorted,
                     wb);
  hipLaunchKernelGGL(scan_kernel, dim3(DIMX), dim3(1024), 0, stream, W1, b1,
                     W2, b2, idx_sorted, SCp);
  hipLaunchKernelGGL(attn_kernel, dim3(NROWS), dim3(1024), 0, stream, pos,
                     mask, kk, qvp, t_sorted, SCp, att);
  hipLaunchKernelGGL(tail_kernel, dim3(NROWS / 2), dim3(1024), 0, stream, att,
                     x, (const uint2*)(wb + WB_WO), bo, ln1g, ln1b,
                     (const uint2*)(wb + WB_WF1), bf1,
                     (const uint2*)(wb + WB_WF2), bf2, ln2g, ln2b, outp);
}